// Round 4
// baseline (533.475 us; speedup 1.0000x reference)
//
#include <hip/hip_runtime.h>

// HeteroGNN fused implementation, round 4.
// Algebra: new = relu( S @ W1 + deg.*(x @ W2) + x @ W3 + deg.*bmp + bu )
// Round-4: layer-2 GEMM rewritten (8x8 micro-tile, conflict-free split-col
// fragments, double-buffered LDS, merged both relations into one dispatch);
// gathers merged + vectorized.

#define H 128
#define NN 50000
#define NL 50000
#define NE 400000
#define NG 64
#define FR 8
#define SNB 49

// ---------------- weight fusion ----------------
__global__ void precompute_w(const float* __restrict__ Wm_nl, const float* __restrict__ bm_nl,
                             const float* __restrict__ Wu_nl,
                             const float* __restrict__ Wm_ln, const float* __restrict__ bm_ln,
                             const float* __restrict__ Wu_ln,
                             float* __restrict__ Wstack, float* __restrict__ bmp) {
    int idx = blockIdx.x * blockDim.x + threadIdx.x;
    const int per = 384 * H + H;
    int c = idx / per, r = idx % per;
    if (c >= 4) return;
    int l = c >> 1, rel = c & 1;
    const float* Wm = (rel ? Wm_ln : Wm_nl) + l * 256 * H;
    const float* Wu = (rel ? Wu_ln : Wu_nl) + l * 256 * H;
    const float* bm = (rel ? bm_ln : bm_nl) + l * H;
    float* Ws = Wstack + c * 384 * H;
    if (r < 384 * H) {
        int t = r / H, j = r % H;
        if (t < 256) {
            float acc = 0.f;
            for (int k = 0; k < H; ++k) acc += Wm[t * H + k] * Wu[k * H + j];
            Ws[t * H + j] = acc;
        } else {
            Ws[t * H + j] = Wu[(t - 128) * H + j];
        }
    } else {
        int j = r - 384 * H;
        float acc = 0.f;
        for (int k = 0; k < H; ++k) acc += bm[k] * Wu[k * H + j];
        bmp[c * H + j] = acc;
    }
}

// ---------------- degree (int) ----------------
__global__ void compute_deg(const int* __restrict__ nl, const int* __restrict__ ln,
                            int* __restrict__ dl, int* __restrict__ dn) {
    int e = blockIdx.x * blockDim.x + threadIdx.x;
    if (e < NE) {
        atomicAdd(&dl[nl[NE + e]], 1);
        atomicAdd(&dn[ln[NE + e]], 1);
    }
}

// ---------------- 3-phase parallel scan ----------------
__global__ void scan1(const int* __restrict__ degL, const int* __restrict__ degN,
                      int* __restrict__ bsum) {
    int arr = blockIdx.x / SNB, blk = blockIdx.x % SNB;
    const int* deg = arr ? degN : degL;
    int tid = threadIdx.x;
    int base = blk * 1024 + tid * 4;
    int s = 0;
#pragma unroll
    for (int i = 0; i < 4; ++i) { int idx = base + i; if (idx < NL) s += deg[idx]; }
    __shared__ int red[256];
    red[tid] = s;
    __syncthreads();
    for (int d = 128; d > 0; d >>= 1) {
        if (tid < d) red[tid] += red[tid + d];
        __syncthreads();
    }
    if (tid == 0) bsum[blockIdx.x] = red[0];
}

__global__ void scan2(const int* __restrict__ bsum, int* __restrict__ bbase) {
    __shared__ int sh[128];
    int tid = threadIdx.x;
    int v0 = (tid < 2 * SNB) ? bsum[tid] : 0;
    sh[tid] = v0;
    __syncthreads();
    int gstart = (tid < SNB) ? 0 : SNB;
    for (int d = 1; d < 64; d <<= 1) {
        int v = (tid >= gstart + d && tid < 2 * SNB) ? sh[tid - d] : 0;
        __syncthreads();
        sh[tid] += v;
        __syncthreads();
    }
    if (tid < 2 * SNB) bbase[tid] = sh[tid] - v0;
}

__global__ void scan3(const int* __restrict__ degL, const int* __restrict__ degN,
                      const int* __restrict__ bbase,
                      int* __restrict__ offL, int* __restrict__ offN,
                      int* __restrict__ curL, int* __restrict__ curN,
                      float* __restrict__ fdegL, float* __restrict__ fdegN) {
    int arr = blockIdx.x / SNB, blk = blockIdx.x % SNB;
    const int* deg = arr ? degN : degL;
    int* off = arr ? offN : offL;
    int* cur = arr ? curN : curL;
    float* fdeg = arr ? fdegN : fdegL;
    int tid = threadIdx.x;
    int base = blk * 1024 + tid * 4;
    int d4[4]; int s = 0;
#pragma unroll
    for (int i = 0; i < 4; ++i) {
        int idx = base + i;
        d4[i] = (idx < NL) ? deg[idx] : 0;
        s += d4[i];
    }
    __shared__ int part[256];
    part[tid] = s;
    __syncthreads();
    for (int d = 1; d < 256; d <<= 1) {
        int v = (tid >= d) ? part[tid - d] : 0;
        __syncthreads();
        part[tid] += v;
        __syncthreads();
    }
    int run = bbase[blockIdx.x] + part[tid] - s;
#pragma unroll
    for (int i = 0; i < 4; ++i) {
        int idx = base + i;
        if (idx < NL) {
            off[idx] = run; cur[idx] = run; fdeg[idx] = (float)d4[i];
            run += d4[i];
            if (idx == NL - 1) off[NL] = run;
        }
    }
}

// ---------------- CSR fill ----------------
__global__ void fill_csr(const int* __restrict__ nl, const int* __restrict__ ln,
                         int* __restrict__ curL, int* __restrict__ curN,
                         int* __restrict__ adjL, int* __restrict__ adjN) {
    int e = blockIdx.x * blockDim.x + threadIdx.x;
    if (e >= NE) return;
    {
        int src = nl[e], dst = nl[NE + e];
        int p = atomicAdd(&curL[dst], 1);
        adjL[p] = src;
    }
    {
        int src = ln[e], dst = ln[NE + e];
        int p = atomicAdd(&curN[dst], 1);
        adjN[p] = src;
    }
}

// ---------------- layer-1 gather (raw 8-col), both relations ----------------
__launch_bounds__(256)
__global__ void gather_sum8_2(const int* __restrict__ offL, const int* __restrict__ adjL,
                              const float* __restrict__ xnode, float* __restrict__ S8l,
                              const int* __restrict__ offN, const int* __restrict__ adjN,
                              const float* __restrict__ xlink, float* __restrict__ S8n) {
    int rel = blockIdx.y;
    const int* off = rel ? offN : offL;
    const int* adj = rel ? adjN : adjL;
    const float* Xr = rel ? xlink : xnode;
    float* S8 = rel ? S8n : S8l;
    int t = blockIdx.x * 256 + threadIdx.x;
    int row = t >> 3, c = t & 7;
    if (row >= NL) return;
    int beg = off[row], end = off[row + 1];
    float acc = 0.f;
    for (int i = beg; i < end; ++i)
        acc += Xr[(size_t)adj[i] * FR + c];
    S8[row * FR + c] = acc;
}

// ---------------- layer-2 gather, both relations, 32-lane float4 rows ----------------
__launch_bounds__(256)
__global__ void gather_sum2(const int* __restrict__ offL, const int* __restrict__ adjL,
                            const float* __restrict__ xnp, float* __restrict__ Sl,
                            const int* __restrict__ offN, const int* __restrict__ adjN,
                            const float* __restrict__ xlp, float* __restrict__ Sn) {
    int rel = blockIdx.y;
    const int* off = rel ? offN : offL;
    const int* adj = rel ? adjN : adjL;
    const float* X = rel ? xlp : xnp;
    float* Sg = rel ? Sn : Sl;
    int row = blockIdx.x * 8 + (threadIdx.x >> 5);
    int lane = threadIdx.x & 31;
    if (row >= NL) return;
    int beg = off[row], end = off[row + 1];
    float ax = 0.f, ay = 0.f, az = 0.f, aw = 0.f;
    float bx = 0.f, by = 0.f, bz = 0.f, bw = 0.f;
    int i = beg;
    for (; i + 1 < end; i += 2) {
        float4 a = *(const float4*)(X + (size_t)adj[i] * H + lane * 4);
        float4 b = *(const float4*)(X + (size_t)adj[i + 1] * H + lane * 4);
        ax += a.x; ay += a.y; az += a.z; aw += a.w;
        bx += b.x; by += b.y; bz += b.z; bw += b.w;
    }
    if (i < end) {
        float4 a = *(const float4*)(X + (size_t)adj[i] * H + lane * 4);
        ax += a.x; ay += a.y; az += a.z; aw += a.w;
    }
    float4 r = make_float4(ax + bx, ay + by, az + bz, aw + bw);
    *(float4*)(Sg + (size_t)row * H + lane * 4) = r;
}

// ---------------- layer-2 fused GEMM, both relations ----------------
// Out = relu([S | deg.*X | X] @ Ws + deg.*bmp + bu); BM=128, BK=16, 8x8 micro.
#define GM 128
#define GK 16
#define ASTR 132
#define BSTR 136

__launch_bounds__(256)
__global__ void gemm_update2(const float* __restrict__ Sl, const float* __restrict__ xlp,
                             const float* __restrict__ dgl,
                             const float* __restrict__ Sn, const float* __restrict__ xnp,
                             const float* __restrict__ dgn,
                             const float* __restrict__ Wstack, const float* __restrict__ bmpAll,
                             const float* __restrict__ bu_nl, const float* __restrict__ bu_ln,
                             float* __restrict__ outl, float* __restrict__ outn, int M) {
    int rel = blockIdx.y;
    const float* S   = rel ? Sn : Sl;
    const float* X   = rel ? xnp : xlp;
    const float* deg = rel ? dgn : dgl;
    const float* Ws  = Wstack + (size_t)(2 + rel) * 384 * H;
    const float* bmp = bmpAll + (2 + rel) * H;
    const float* bu  = (rel ? bu_ln : bu_nl) + H;   // layer index 1
    float* Out = rel ? outn : outl;

    __shared__ float At[2][GK][ASTR];
    __shared__ float Bt[2][GK][BSTR];

    int tid = threadIdx.x;
    int rowt = tid >> 4, colt = tid & 15;
    int m0 = blockIdx.x * GM;

    // staging ids: A: two float4s (rows r0, r0+64, k-chunk kg)
    int r0 = tid >> 2;
    int kg = tid & 3;
    int row0 = m0 + r0, row1 = m0 + r0 + 64;
    bool v0 = row0 < M, v1 = row1 < M;
    float d0 = v0 ? deg[row0] : 0.f;
    float d1 = v1 ? deg[row1] : 0.f;
    int kkb = tid >> 5, c4 = tid & 31;   // B staging

    float4 pa0, pa1, pb0, pb1;
    // prologue: k0 = 0 (piece 0 = S)
    {
        int kin = kg * 4;
        pa0 = v0 ? *(const float4*)(S + (size_t)row0 * H + kin) : make_float4(0.f, 0.f, 0.f, 0.f);
        pa1 = v1 ? *(const float4*)(S + (size_t)row1 * H + kin) : make_float4(0.f, 0.f, 0.f, 0.f);
        pb0 = *(const float4*)(Ws + tid * 4);
        pb1 = *(const float4*)(Ws + (tid + 256) * 4);
        At[0][kg * 4 + 0][r0] = pa0.x; At[0][kg * 4 + 1][r0] = pa0.y;
        At[0][kg * 4 + 2][r0] = pa0.z; At[0][kg * 4 + 3][r0] = pa0.w;
        At[0][kg * 4 + 0][r0 + 64] = pa1.x; At[0][kg * 4 + 1][r0 + 64] = pa1.y;
        At[0][kg * 4 + 2][r0 + 64] = pa1.z; At[0][kg * 4 + 3][r0 + 64] = pa1.w;
        *(float4*)&Bt[0][kkb][c4 * 4] = pb0;
        *(float4*)&Bt[0][kkb + 8][c4 * 4] = pb1;
    }
    __syncthreads();

    float acc[8][8] = {};
    for (int k0 = 0; k0 < 24; ++k0) {
        int cur = k0 & 1;
        if (k0 < 23) {
            int kbase = (k0 + 1) * GK;
            int piece = kbase >> 7;          // 0:S 1:deg*X 2:X
            int kin = (kbase & 127) + kg * 4;
            const float* Asrc = (piece == 0) ? S : X;
            pa0 = v0 ? *(const float4*)(Asrc + (size_t)row0 * H + kin) : make_float4(0.f, 0.f, 0.f, 0.f);
            pa1 = v1 ? *(const float4*)(Asrc + (size_t)row1 * H + kin) : make_float4(0.f, 0.f, 0.f, 0.f);
            if (piece == 1) {
                pa0.x *= d0; pa0.y *= d0; pa0.z *= d0; pa0.w *= d0;
                pa1.x *= d1; pa1.y *= d1; pa1.z *= d1; pa1.w *= d1;
            }
            pb0 = *(const float4*)(Ws + (size_t)kbase * H + tid * 4);
            pb1 = *(const float4*)(Ws + (size_t)kbase * H + (tid + 256) * 4);
        }
#pragma unroll
        for (int kk = 0; kk < GK; ++kk) {
            float a[8], b[8];
            *(float4*)(a)     = *(const float4*)&At[cur][kk][rowt * 4];
            *(float4*)(a + 4) = *(const float4*)&At[cur][kk][64 + rowt * 4];
            *(float4*)(b)     = *(const float4*)&Bt[cur][kk][colt * 4];
            *(float4*)(b + 4) = *(const float4*)&Bt[cur][kk][64 + colt * 4];
#pragma unroll
            for (int i = 0; i < 8; ++i)
#pragma unroll
                for (int j = 0; j < 8; ++j)
                    acc[i][j] += a[i] * b[j];
        }
        if (k0 < 23) {
            int nxt = cur ^ 1;
            At[nxt][kg * 4 + 0][r0] = pa0.x; At[nxt][kg * 4 + 1][r0] = pa0.y;
            At[nxt][kg * 4 + 2][r0] = pa0.z; At[nxt][kg * 4 + 3][r0] = pa0.w;
            At[nxt][kg * 4 + 0][r0 + 64] = pa1.x; At[nxt][kg * 4 + 1][r0 + 64] = pa1.y;
            At[nxt][kg * 4 + 2][r0 + 64] = pa1.z; At[nxt][kg * 4 + 3][r0 + 64] = pa1.w;
            *(float4*)&Bt[nxt][kkb][c4 * 4] = pb0;
            *(float4*)&Bt[nxt][kkb + 8][c4 * 4] = pb1;
        }
        __syncthreads();
    }

    int c0 = colt * 4, c1 = 64 + colt * 4;
    float4 bm0 = *(const float4*)(bmp + c0), bm1 = *(const float4*)(bmp + c1);
    float4 bb0 = *(const float4*)(bu + c0),  bb1 = *(const float4*)(bu + c1);
#pragma unroll
    for (int i = 0; i < 8; ++i) {
        int row = m0 + (i < 4 ? rowt * 4 + i : 64 + rowt * 4 + (i - 4));
        if (row < M) {
            float d = deg[row];
            float4 o0, o1;
            o0.x = fmaxf(acc[i][0] + d * bm0.x + bb0.x, 0.f);
            o0.y = fmaxf(acc[i][1] + d * bm0.y + bb0.y, 0.f);
            o0.z = fmaxf(acc[i][2] + d * bm0.z + bb0.z, 0.f);
            o0.w = fmaxf(acc[i][3] + d * bm0.w + bb0.w, 0.f);
            o1.x = fmaxf(acc[i][4] + d * bm1.x + bb1.x, 0.f);
            o1.y = fmaxf(acc[i][5] + d * bm1.y + bb1.y, 0.f);
            o1.z = fmaxf(acc[i][6] + d * bm1.z + bb1.z, 0.f);
            o1.w = fmaxf(acc[i][7] + d * bm1.w + bb1.w, 0.f);
            *(float4*)(Out + (size_t)row * H + c0) = o0;
            *(float4*)(Out + (size_t)row * H + c1) = o1;
        }
    }
}

// ---------------- layer-1 fused GEMM (K=24), both relations ----------------
#define BM 64
__launch_bounds__(256)
__global__ void gemm_update_l1_2(const float* __restrict__ S8l, const float* __restrict__ xlink,
                                 const float* __restrict__ dgl,
                                 const float* __restrict__ S8n, const float* __restrict__ xnode,
                                 const float* __restrict__ dgn,
                                 const float* __restrict__ Wstack, const float* __restrict__ bmpAll,
                                 const float* __restrict__ bu_nl, const float* __restrict__ bu_ln,
                                 float* __restrict__ outl, float* __restrict__ outn, int M) {
    int rel = blockIdx.y;
    const float* S8  = rel ? S8n : S8l;
    const float* Xr  = rel ? xnode : xlink;
    const float* deg = rel ? dgn : dgl;
    const float* Ws  = Wstack + (size_t)rel * 384 * H;
    const float* bmp = bmpAll + rel * H;
    const float* bu  = rel ? bu_ln : bu_nl;
    float* Out = rel ? outn : outl;

    __shared__ float At[24][BM + 4];
    __shared__ float Bt[24][H];
    int tid = threadIdx.x;
    int rowg = tid >> 4;
    int colg = tid & 15;
    int m0 = blockIdx.x * BM;

#pragma unroll
    for (int p = 0; p < 6; ++p) {
        int lin = tid + p * 256;
        int r = lin / 24, k = lin % 24;
        int row = m0 + r;
        float v = 0.f;
        if (row < M) {
            if (k < 8)       v = S8[row * FR + k];
            else if (k < 16) v = deg[row] * Xr[(size_t)row * FR + (k - 8)];
            else             v = Xr[(size_t)row * FR + (k - 16)];
        }
        At[k][r] = v;
    }
#pragma unroll
    for (int p = 0; p < 12; ++p) {
        int lin = tid + p * 256;
        int kk = lin >> 7, c = lin & 127;
        int srcrow = (kk >> 3) * 128 + (kk & 7);
        Bt[kk][c] = Ws[srcrow * H + c];
    }
    __syncthreads();

    float acc[4][8] = {};
#pragma unroll
    for (int kk = 0; kk < 24; ++kk) {
        float a[4], b[8];
        *(float4*)a = *(const float4*)(&At[kk][rowg * 4]);
        *(float4*)(b) = *(const float4*)(&Bt[kk][colg * 8]);
        *(float4*)(b + 4) = *(const float4*)(&Bt[kk][colg * 8 + 4]);
#pragma unroll
        for (int i = 0; i < 4; ++i)
#pragma unroll
            for (int j = 0; j < 8; ++j)
                acc[i][j] += a[i] * b[j];
    }

    int colbase = colg * 8;
    float bmv[8], buv[8];
#pragma unroll
    for (int j = 0; j < 8; ++j) { bmv[j] = bmp[colbase + j]; buv[j] = bu[colbase + j]; }
#pragma unroll
    for (int i = 0; i < 4; ++i) {
        int row = m0 + rowg * 4 + i;
        if (row < M) {
            float d = deg[row];
            float o[8];
#pragma unroll
            for (int j = 0; j < 8; ++j) {
                float v = acc[i][j] + d * bmv[j] + buv[j];
                o[j] = v > 0.f ? v : 0.f;
            }
            *(float4*)(Out + (size_t)row * H + colbase) = *(float4*)o;
            *(float4*)(Out + (size_t)row * H + colbase + 4) = *(float4*)(o + 4);
        }
    }
}

// ---------------- global mean pool ----------------
#define PR 256
__global__ void pool_sum(const float* __restrict__ xl, const int* __restrict__ batch,
                         float* __restrict__ sums) {
    int base = blockIdx.x * PR;
    int col = threadIdx.x & 127;
    int half = threadIdx.x >> 7;
    int rows = min(PR, NL - base);
    float acc = 0.f;
    int cur = -1;
    for (int r = half; r < rows; r += 2) {
        int row = base + r;
        int g = batch[row];
        if (g != cur) {
            if (cur >= 0) atomicAdd(&sums[cur * H + col], acc);
            acc = 0.f;
            cur = g;
        }
        acc += xl[(size_t)row * H + col];
    }
    if (cur >= 0) atomicAdd(&sums[cur * H + col], acc);
}

__global__ void pool_counts(const int* __restrict__ batch, float* __restrict__ cnt) {
    int g = threadIdx.x;
    if (g >= NG) return;
    int lo = 0, hi = NL;
    while (lo < hi) { int mid = (lo + hi) >> 1; if (batch[mid] < g) lo = mid + 1; else hi = mid; }
    int first = lo;
    lo = 0; hi = NL;
    while (lo < hi) { int mid = (lo + hi) >> 1; if (batch[mid] < g + 1) lo = mid + 1; else hi = mid; }
    cnt[g] = (float)(lo - first);
}

__global__ void pool_final(const float* __restrict__ sums, const float* __restrict__ cnt,
                           float* __restrict__ out) {
    int idx = blockIdx.x * blockDim.x + threadIdx.x;
    int g = idx / H;
    out[idx] = sums[idx] / fmaxf(cnt[g], 1.f);
}

static inline size_t rup(size_t n) { return (n + 15) & ~(size_t)15; }

extern "C" void kernel_launch(void* const* d_in, const int* in_sizes, int n_in,
                              void* d_out, int out_size, void* d_ws, size_t ws_size,
                              hipStream_t stream) {
    const float* x_node = (const float*)d_in[0];
    const float* x_link = (const float*)d_in[1];
    const float* Wm_nl  = (const float*)d_in[2];
    const float* bm_nl  = (const float*)d_in[3];
    const float* Wu_nl  = (const float*)d_in[4];
    const float* bu_nl  = (const float*)d_in[5];
    const float* Wm_ln  = (const float*)d_in[6];
    const float* bm_ln  = (const float*)d_in[7];
    const float* Wu_ln  = (const float*)d_in[8];
    const float* bu_ln  = (const float*)d_in[9];
    const int* nl_edge  = (const int*)d_in[10];
    const int* ln_edge  = (const int*)d_in[11];
    const int* batch_link = (const int*)d_in[12];
    (void)in_sizes; (void)n_in; (void)out_size; (void)ws_size;

    char* wsb = (char*)d_ws;
    size_t o = 0;
    auto alloc = [&](size_t elems) { void* p = wsb + o * 4; o += rup(elems); return p; };
    float* xn    = (float*)alloc((size_t)NN * H);
    float* xl    = (float*)alloc((size_t)NL * H);
    float* Sl    = (float*)alloc((size_t)NL * H);   // doubles as S8l (layer 1)
    float* Sn    = (float*)alloc((size_t)NN * H);   // doubles as S8n (layer 1)
    float* deg_l = (float*)alloc(NL);
    float* deg_n = (float*)alloc(NN);
    int*   idl   = (int*)alloc(NL);
    int*   idn   = (int*)alloc(NN);
    int*   offL  = (int*)alloc(NL + 1);
    int*   offN  = (int*)alloc(NN + 1);
    int*   curL  = (int*)alloc(NL);
    int*   curN  = (int*)alloc(NN);
    int*   adjL  = (int*)alloc(NE);
    int*   adjN  = (int*)alloc(NE);
    float* Wstack= (float*)alloc(4L * 384 * H);
    float* bmp   = (float*)alloc(4 * H);
    float* sums  = (float*)alloc(NG * H);
    float* cnt   = (float*)alloc(NG);
    int*   bsum  = (int*)alloc(2 * SNB);
    int*   bbase = (int*)alloc(2 * SNB);

    hipMemsetAsync(idl, 0, (size_t)(rup(NL) + NN) * sizeof(int), stream);
    hipMemsetAsync(sums, 0, (size_t)NG * H * sizeof(float), stream);

    precompute_w<<<(4 * (384 * H + H) + 255) / 256, 256, 0, stream>>>(
        Wm_nl, bm_nl, Wu_nl, Wm_ln, bm_ln, Wu_ln, Wstack, bmp);
    compute_deg<<<(NE + 255) / 256, 256, 0, stream>>>(nl_edge, ln_edge, idl, idn);
    scan1<<<2 * SNB, 256, 0, stream>>>(idl, idn, bsum);
    scan2<<<1, 128, 0, stream>>>(bsum, bbase);
    scan3<<<2 * SNB, 256, 0, stream>>>(idl, idn, bbase, offL, offN, curL, curN, deg_l, deg_n);
    fill_csr<<<(NE + 255) / 256, 256, 0, stream>>>(nl_edge, ln_edge, curL, curN, adjL, adjN);
    pool_counts<<<1, 64, 0, stream>>>(batch_link, cnt);

    // ---- layer 1 ----
    gather_sum8_2<<<dim3((NL * FR + 255) / 256, 2), 256, 0, stream>>>(
        offL, adjL, x_node, Sl, offN, adjN, x_link, Sn);
    gemm_update_l1_2<<<dim3((NL + BM - 1) / BM, 2), 256, 0, stream>>>(
        Sl, x_link, deg_l, Sn, x_node, deg_n, Wstack, bmp, bu_nl, bu_ln, xl, xn, NL);

    // ---- layer 2 ----
    gather_sum2<<<dim3((NL + 7) / 8, 2), 256, 0, stream>>>(
        offL, adjL, xn, Sl, offN, adjN, xl, Sn);
    gemm_update2<<<dim3((NL + GM - 1) / GM, 2), 256, 0, stream>>>(
        Sl, xl, deg_l, Sn, xn, deg_n, Wstack, bmp, bu_nl, bu_ln, xl, xn, NL);

    pool_sum<<<(NL + PR - 1) / PR, 256, 0, stream>>>(xl, batch_link, sums);
    pool_final<<<(NG * H) / 256, 256, 0, stream>>>(sums, cnt, (float*)d_out);
}

// Round 5
// 428.734 us; speedup vs baseline: 1.2443x; 1.2443x over previous
//
#include <hip/hip_runtime.h>

// HeteroGNN fused implementation, round 5.
// Algebra: new = relu( S @ W1 + deg.*(x @ W2) + x @ W3 + deg.*bmp + bu )
// Round-5: revert layer-2 GEMM to round-3 structure (single-buffer, 4x8 micro,
// 52 VGPR) with two fixes: split-column B fragments (kills 4-way LDS bank
// conflict) and merged-relation dispatch (1564 blocks = 6/CU, matches LDS
// occupancy ceiling). Round-4's 8x8 double-buffer (184 VGPR, 9% occ) dropped.

#define H 128
#define NN 50000
#define NL 50000
#define NE 400000
#define NG 64
#define FR 8
#define SNB 49

// ---------------- weight fusion ----------------
__global__ void precompute_w(const float* __restrict__ Wm_nl, const float* __restrict__ bm_nl,
                             const float* __restrict__ Wu_nl,
                             const float* __restrict__ Wm_ln, const float* __restrict__ bm_ln,
                             const float* __restrict__ Wu_ln,
                             float* __restrict__ Wstack, float* __restrict__ bmp) {
    int idx = blockIdx.x * blockDim.x + threadIdx.x;
    const int per = 384 * H + H;
    int c = idx / per, r = idx % per;
    if (c >= 4) return;
    int l = c >> 1, rel = c & 1;
    const float* Wm = (rel ? Wm_ln : Wm_nl) + l * 256 * H;
    const float* Wu = (rel ? Wu_ln : Wu_nl) + l * 256 * H;
    const float* bm = (rel ? bm_ln : bm_nl) + l * H;
    float* Ws = Wstack + c * 384 * H;
    if (r < 384 * H) {
        int t = r / H, j = r % H;
        if (t < 256) {
            float acc = 0.f;
            for (int k = 0; k < H; ++k) acc += Wm[t * H + k] * Wu[k * H + j];
            Ws[t * H + j] = acc;
        } else {
            Ws[t * H + j] = Wu[(t - 128) * H + j];
        }
    } else {
        int j = r - 384 * H;
        float acc = 0.f;
        for (int k = 0; k < H; ++k) acc += bm[k] * Wu[k * H + j];
        bmp[c * H + j] = acc;
    }
}

// ---------------- degree (int) ----------------
__global__ void compute_deg(const int* __restrict__ nl, const int* __restrict__ ln,
                            int* __restrict__ dl, int* __restrict__ dn) {
    int e = blockIdx.x * blockDim.x + threadIdx.x;
    if (e < NE) {
        atomicAdd(&dl[nl[NE + e]], 1);
        atomicAdd(&dn[ln[NE + e]], 1);
    }
}

// ---------------- 3-phase parallel scan ----------------
__global__ void scan1(const int* __restrict__ degL, const int* __restrict__ degN,
                      int* __restrict__ bsum) {
    int arr = blockIdx.x / SNB, blk = blockIdx.x % SNB;
    const int* deg = arr ? degN : degL;
    int tid = threadIdx.x;
    int base = blk * 1024 + tid * 4;
    int s = 0;
#pragma unroll
    for (int i = 0; i < 4; ++i) { int idx = base + i; if (idx < NL) s += deg[idx]; }
    __shared__ int red[256];
    red[tid] = s;
    __syncthreads();
    for (int d = 128; d > 0; d >>= 1) {
        if (tid < d) red[tid] += red[tid + d];
        __syncthreads();
    }
    if (tid == 0) bsum[blockIdx.x] = red[0];
}

__global__ void scan2(const int* __restrict__ bsum, int* __restrict__ bbase) {
    __shared__ int sh[128];
    int tid = threadIdx.x;
    int v0 = (tid < 2 * SNB) ? bsum[tid] : 0;
    sh[tid] = v0;
    __syncthreads();
    int gstart = (tid < SNB) ? 0 : SNB;
    for (int d = 1; d < 64; d <<= 1) {
        int v = (tid >= gstart + d && tid < 2 * SNB) ? sh[tid - d] : 0;
        __syncthreads();
        sh[tid] += v;
        __syncthreads();
    }
    if (tid < 2 * SNB) bbase[tid] = sh[tid] - v0;
}

__global__ void scan3(const int* __restrict__ degL, const int* __restrict__ degN,
                      const int* __restrict__ bbase,
                      int* __restrict__ offL, int* __restrict__ offN,
                      int* __restrict__ curL, int* __restrict__ curN,
                      float* __restrict__ fdegL, float* __restrict__ fdegN) {
    int arr = blockIdx.x / SNB, blk = blockIdx.x % SNB;
    const int* deg = arr ? degN : degL;
    int* off = arr ? offN : offL;
    int* cur = arr ? curN : curL;
    float* fdeg = arr ? fdegN : fdegL;
    int tid = threadIdx.x;
    int base = blk * 1024 + tid * 4;
    int d4[4]; int s = 0;
#pragma unroll
    for (int i = 0; i < 4; ++i) {
        int idx = base + i;
        d4[i] = (idx < NL) ? deg[idx] : 0;
        s += d4[i];
    }
    __shared__ int part[256];
    part[tid] = s;
    __syncthreads();
    for (int d = 1; d < 256; d <<= 1) {
        int v = (tid >= d) ? part[tid - d] : 0;
        __syncthreads();
        part[tid] += v;
        __syncthreads();
    }
    int run = bbase[blockIdx.x] + part[tid] - s;
#pragma unroll
    for (int i = 0; i < 4; ++i) {
        int idx = base + i;
        if (idx < NL) {
            off[idx] = run; cur[idx] = run; fdeg[idx] = (float)d4[i];
            run += d4[i];
            if (idx == NL - 1) off[NL] = run;
        }
    }
}

// ---------------- CSR fill ----------------
__global__ void fill_csr(const int* __restrict__ nl, const int* __restrict__ ln,
                         int* __restrict__ curL, int* __restrict__ curN,
                         int* __restrict__ adjL, int* __restrict__ adjN) {
    int e = blockIdx.x * blockDim.x + threadIdx.x;
    if (e >= NE) return;
    {
        int src = nl[e], dst = nl[NE + e];
        int p = atomicAdd(&curL[dst], 1);
        adjL[p] = src;
    }
    {
        int src = ln[e], dst = ln[NE + e];
        int p = atomicAdd(&curN[dst], 1);
        adjN[p] = src;
    }
}

// ---------------- layer-1 gather (raw 8-col), both relations ----------------
__launch_bounds__(256)
__global__ void gather_sum8_2(const int* __restrict__ offL, const int* __restrict__ adjL,
                              const float* __restrict__ xnode, float* __restrict__ S8l,
                              const int* __restrict__ offN, const int* __restrict__ adjN,
                              const float* __restrict__ xlink, float* __restrict__ S8n) {
    int rel = blockIdx.y;
    const int* off = rel ? offN : offL;
    const int* adj = rel ? adjN : adjL;
    const float* Xr = rel ? xlink : xnode;
    float* S8 = rel ? S8n : S8l;
    int t = blockIdx.x * 256 + threadIdx.x;
    int row = t >> 3, c = t & 7;
    if (row >= NL) return;
    int beg = off[row], end = off[row + 1];
    float acc = 0.f;
    for (int i = beg; i < end; ++i)
        acc += Xr[(size_t)adj[i] * FR + c];
    S8[row * FR + c] = acc;
}

// ---------------- layer-2 gather, both relations, 32-lane float4 rows ----------------
__launch_bounds__(256)
__global__ void gather_sum2(const int* __restrict__ offL, const int* __restrict__ adjL,
                            const float* __restrict__ xnp, float* __restrict__ Sl,
                            const int* __restrict__ offN, const int* __restrict__ adjN,
                            const float* __restrict__ xlp, float* __restrict__ Sn) {
    int rel = blockIdx.y;
    const int* off = rel ? offN : offL;
    const int* adj = rel ? adjN : adjL;
    const float* X = rel ? xlp : xnp;
    float* Sg = rel ? Sn : Sl;
    int row = blockIdx.x * 8 + (threadIdx.x >> 5);
    int lane = threadIdx.x & 31;
    if (row >= NL) return;
    int beg = off[row], end = off[row + 1];
    float ax = 0.f, ay = 0.f, az = 0.f, aw = 0.f;
    float bx = 0.f, by = 0.f, bz = 0.f, bw = 0.f;
    int i = beg;
    for (; i + 1 < end; i += 2) {
        float4 a = *(const float4*)(X + (size_t)adj[i] * H + lane * 4);
        float4 b = *(const float4*)(X + (size_t)adj[i + 1] * H + lane * 4);
        ax += a.x; ay += a.y; az += a.z; aw += a.w;
        bx += b.x; by += b.y; bz += b.z; bw += b.w;
    }
    if (i < end) {
        float4 a = *(const float4*)(X + (size_t)adj[i] * H + lane * 4);
        ax += a.x; ay += a.y; az += a.z; aw += a.w;
    }
    float4 r = make_float4(ax + bx, ay + by, az + bz, aw + bw);
    *(float4*)(Sg + (size_t)row * H + lane * 4) = r;
}

// ---------------- layer-2 fused GEMM, both relations (round-3 structure) ----------------
// Out = relu([S | deg.*X | X] @ Ws + deg.*bmp + bu); BM=64, BK=32, 4x8 micro,
// split-column B fragments (cols colg*4 and 64+colg*4) -> conflict-free reads.
#define BM 64
#define BK 32
__launch_bounds__(256)
__global__ void gemm_update3(const float* __restrict__ Sl, const float* __restrict__ xlp,
                             const float* __restrict__ dgl,
                             const float* __restrict__ Sn, const float* __restrict__ xnp,
                             const float* __restrict__ dgn,
                             const float* __restrict__ Wstack, const float* __restrict__ bmpAll,
                             const float* __restrict__ bu_nl, const float* __restrict__ bu_ln,
                             float* __restrict__ outl, float* __restrict__ outn, int M) {
    int rel = blockIdx.y;
    const float* S   = rel ? Sn : Sl;
    const float* X   = rel ? xnp : xlp;
    const float* deg = rel ? dgn : dgl;
    const float* Ws  = Wstack + (size_t)(2 + rel) * 384 * H;
    const float* bmp = bmpAll + (2 + rel) * H;
    const float* bu  = (rel ? bu_ln : bu_nl) + H;   // layer index 1
    float* Out = rel ? outn : outl;

    __shared__ float At[BK][BM + 4];   // [k][m], 32x68
    __shared__ float Bt[BK][H];        // 32x128
    int tid = threadIdx.x;
    int rowg = tid >> 4;     // 0..15 -> 4 rows each
    int colg = tid & 15;     // 0..15 -> cols {colg*4, 64+colg*4}
    int m0 = blockIdx.x * BM;
    float acc[4][8] = {};

    for (int k0 = 0; k0 < 384; k0 += BK) {
        // stage A: 64 rows x 32 k
#pragma unroll
        for (int p = 0; p < 2; ++p) {
            int idx = tid + p * 256;
            int r = idx >> 3, kg = idx & 7;
            int row = m0 + r;
            int k = k0 + kg * 4;
            float4 v = make_float4(0.f, 0.f, 0.f, 0.f);
            if (row < M) {
                if (k < 128) {
                    v = *(const float4*)(S + (size_t)row * H + k);
                } else if (k < 256) {
                    v = *(const float4*)(X + (size_t)row * H + (k - 128));
                    float d = deg[row];
                    v.x *= d; v.y *= d; v.z *= d; v.w *= d;
                } else {
                    v = *(const float4*)(X + (size_t)row * H + (k - 256));
                }
            }
            At[kg * 4 + 0][r] = v.x;
            At[kg * 4 + 1][r] = v.y;
            At[kg * 4 + 2][r] = v.z;
            At[kg * 4 + 3][r] = v.w;
        }
        // stage B: 32 k-rows x 128 cols
#pragma unroll
        for (int p = 0; p < 4; ++p) {
            int idx = tid + p * 256;
            int kk = idx >> 5, c4 = idx & 31;
            *(float4*)(&Bt[kk][c4 * 4]) = *(const float4*)(Ws + (size_t)(k0 + kk) * H + c4 * 4);
        }
        __syncthreads();
#pragma unroll
        for (int kk = 0; kk < BK; ++kk) {
            float a[4], b[8];
            *(float4*)a = *(const float4*)(&At[kk][rowg * 4]);
            *(float4*)(b)     = *(const float4*)(&Bt[kk][colg * 4]);
            *(float4*)(b + 4) = *(const float4*)(&Bt[kk][64 + colg * 4]);
#pragma unroll
            for (int i = 0; i < 4; ++i)
#pragma unroll
                for (int j = 0; j < 8; ++j)
                    acc[i][j] += a[i] * b[j];
        }
        __syncthreads();
    }

    int c0 = colg * 4, c1 = 64 + colg * 4;
    float4 bm0 = *(const float4*)(bmp + c0), bm1 = *(const float4*)(bmp + c1);
    float4 bb0 = *(const float4*)(bu + c0),  bb1 = *(const float4*)(bu + c1);
#pragma unroll
    for (int i = 0; i < 4; ++i) {
        int row = m0 + rowg * 4 + i;
        if (row < M) {
            float d = deg[row];
            float4 o0, o1;
            o0.x = fmaxf(acc[i][0] + d * bm0.x + bb0.x, 0.f);
            o0.y = fmaxf(acc[i][1] + d * bm0.y + bb0.y, 0.f);
            o0.z = fmaxf(acc[i][2] + d * bm0.z + bb0.z, 0.f);
            o0.w = fmaxf(acc[i][3] + d * bm0.w + bb0.w, 0.f);
            o1.x = fmaxf(acc[i][4] + d * bm1.x + bb1.x, 0.f);
            o1.y = fmaxf(acc[i][5] + d * bm1.y + bb1.y, 0.f);
            o1.z = fmaxf(acc[i][6] + d * bm1.z + bb1.z, 0.f);
            o1.w = fmaxf(acc[i][7] + d * bm1.w + bb1.w, 0.f);
            *(float4*)(Out + (size_t)row * H + c0) = o0;
            *(float4*)(Out + (size_t)row * H + c1) = o1;
        }
    }
}

// ---------------- layer-1 fused GEMM (K=24), both relations ----------------
__launch_bounds__(256)
__global__ void gemm_update_l1_2(const float* __restrict__ S8l, const float* __restrict__ xlink,
                                 const float* __restrict__ dgl,
                                 const float* __restrict__ S8n, const float* __restrict__ xnode,
                                 const float* __restrict__ dgn,
                                 const float* __restrict__ Wstack, const float* __restrict__ bmpAll,
                                 const float* __restrict__ bu_nl, const float* __restrict__ bu_ln,
                                 float* __restrict__ outl, float* __restrict__ outn, int M) {
    int rel = blockIdx.y;
    const float* S8  = rel ? S8n : S8l;
    const float* Xr  = rel ? xnode : xlink;
    const float* deg = rel ? dgn : dgl;
    const float* Ws  = Wstack + (size_t)rel * 384 * H;
    const float* bmp = bmpAll + rel * H;
    const float* bu  = rel ? bu_ln : bu_nl;
    float* Out = rel ? outn : outl;

    __shared__ float At[24][BM + 4];
    __shared__ float Bt[24][H];
    int tid = threadIdx.x;
    int rowg = tid >> 4;
    int colg = tid & 15;
    int m0 = blockIdx.x * BM;

#pragma unroll
    for (int p = 0; p < 6; ++p) {
        int lin = tid + p * 256;
        int r = lin / 24, k = lin % 24;
        int row = m0 + r;
        float v = 0.f;
        if (row < M) {
            if (k < 8)       v = S8[row * FR + k];
            else if (k < 16) v = deg[row] * Xr[(size_t)row * FR + (k - 8)];
            else             v = Xr[(size_t)row * FR + (k - 16)];
        }
        At[k][r] = v;
    }
#pragma unroll
    for (int p = 0; p < 12; ++p) {
        int lin = tid + p * 256;
        int kk = lin >> 7, c = lin & 127;
        int srcrow = (kk >> 3) * 128 + (kk & 7);
        Bt[kk][c] = Ws[srcrow * H + c];
    }
    __syncthreads();

    float acc[4][8] = {};
#pragma unroll
    for (int kk = 0; kk < 24; ++kk) {
        float a[4], b[8];
        *(float4*)a = *(const float4*)(&At[kk][rowg * 4]);
        *(float4*)(b)     = *(const float4*)(&Bt[kk][colg * 4]);
        *(float4*)(b + 4) = *(const float4*)(&Bt[kk][64 + colg * 4]);
#pragma unroll
        for (int i = 0; i < 4; ++i)
#pragma unroll
            for (int j = 0; j < 8; ++j)
                acc[i][j] += a[i] * b[j];
    }

    int c0 = colg * 4, c1 = 64 + colg * 4;
    float bm0[4], bm1[4], bb0[4], bb1[4];
#pragma unroll
    for (int j = 0; j < 4; ++j) {
        bm0[j] = bmp[c0 + j]; bm1[j] = bmp[c1 + j];
        bb0[j] = bu[c0 + j];  bb1[j] = bu[c1 + j];
    }
#pragma unroll
    for (int i = 0; i < 4; ++i) {
        int row = m0 + rowg * 4 + i;
        if (row < M) {
            float d = deg[row];
            float o0[4], o1[4];
#pragma unroll
            for (int j = 0; j < 4; ++j) {
                o0[j] = fmaxf(acc[i][j]     + d * bm0[j] + bb0[j], 0.f);
                o1[j] = fmaxf(acc[i][j + 4] + d * bm1[j] + bb1[j], 0.f);
            }
            *(float4*)(Out + (size_t)row * H + c0) = *(float4*)o0;
            *(float4*)(Out + (size_t)row * H + c1) = *(float4*)o1;
        }
    }
}

// ---------------- global mean pool ----------------
#define PR 256
__global__ void pool_sum(const float* __restrict__ xl, const int* __restrict__ batch,
                         float* __restrict__ sums) {
    int base = blockIdx.x * PR;
    int col = threadIdx.x & 127;
    int half = threadIdx.x >> 7;
    int rows = min(PR, NL - base);
    float acc = 0.f;
    int cur = -1;
    for (int r = half; r < rows; r += 2) {
        int row = base + r;
        int g = batch[row];
        if (g != cur) {
            if (cur >= 0) atomicAdd(&sums[cur * H + col], acc);
            acc = 0.f;
            cur = g;
        }
        acc += xl[(size_t)row * H + col];
    }
    if (cur >= 0) atomicAdd(&sums[cur * H + col], acc);
}

__global__ void pool_counts(const int* __restrict__ batch, float* __restrict__ cnt) {
    int g = threadIdx.x;
    if (g >= NG) return;
    int lo = 0, hi = NL;
    while (lo < hi) { int mid = (lo + hi) >> 1; if (batch[mid] < g) lo = mid + 1; else hi = mid; }
    int first = lo;
    lo = 0; hi = NL;
    while (lo < hi) { int mid = (lo + hi) >> 1; if (batch[mid] < g + 1) lo = mid + 1; else hi = mid; }
    cnt[g] = (float)(lo - first);
}

__global__ void pool_final(const float* __restrict__ sums, const float* __restrict__ cnt,
                           float* __restrict__ out) {
    int idx = blockIdx.x * blockDim.x + threadIdx.x;
    int g = idx / H;
    out[idx] = sums[idx] / fmaxf(cnt[g], 1.f);
}

static inline size_t rup(size_t n) { return (n + 15) & ~(size_t)15; }

extern "C" void kernel_launch(void* const* d_in, const int* in_sizes, int n_in,
                              void* d_out, int out_size, void* d_ws, size_t ws_size,
                              hipStream_t stream) {
    const float* x_node = (const float*)d_in[0];
    const float* x_link = (const float*)d_in[1];
    const float* Wm_nl  = (const float*)d_in[2];
    const float* bm_nl  = (const float*)d_in[3];
    const float* Wu_nl  = (const float*)d_in[4];
    const float* bu_nl  = (const float*)d_in[5];
    const float* Wm_ln  = (const float*)d_in[6];
    const float* bm_ln  = (const float*)d_in[7];
    const float* Wu_ln  = (const float*)d_in[8];
    const float* bu_ln  = (const float*)d_in[9];
    const int* nl_edge  = (const int*)d_in[10];
    const int* ln_edge  = (const int*)d_in[11];
    const int* batch_link = (const int*)d_in[12];
    (void)in_sizes; (void)n_in; (void)out_size; (void)ws_size;

    char* wsb = (char*)d_ws;
    size_t o = 0;
    auto alloc = [&](size_t elems) { void* p = wsb + o * 4; o += rup(elems); return p; };
    float* xn    = (float*)alloc((size_t)NN * H);
    float* xl    = (float*)alloc((size_t)NL * H);
    float* Sl    = (float*)alloc((size_t)NL * H);   // doubles as S8l (layer 1)
    float* Sn    = (float*)alloc((size_t)NN * H);   // doubles as S8n (layer 1)
    float* deg_l = (float*)alloc(NL);
    float* deg_n = (float*)alloc(NN);
    int*   idl   = (int*)alloc(NL);
    int*   idn   = (int*)alloc(NN);
    int*   offL  = (int*)alloc(NL + 1);
    int*   offN  = (int*)alloc(NN + 1);
    int*   curL  = (int*)alloc(NL);
    int*   curN  = (int*)alloc(NN);
    int*   adjL  = (int*)alloc(NE);
    int*   adjN  = (int*)alloc(NE);
    float* Wstack= (float*)alloc(4L * 384 * H);
    float* bmp   = (float*)alloc(4 * H);
    float* sums  = (float*)alloc(NG * H);
    float* cnt   = (float*)alloc(NG);
    int*   bsum  = (int*)alloc(2 * SNB);
    int*   bbase = (int*)alloc(2 * SNB);

    hipMemsetAsync(idl, 0, (size_t)(rup(NL) + NN) * sizeof(int), stream);
    hipMemsetAsync(sums, 0, (size_t)NG * H * sizeof(float), stream);

    precompute_w<<<(4 * (384 * H + H) + 255) / 256, 256, 0, stream>>>(
        Wm_nl, bm_nl, Wu_nl, Wm_ln, bm_ln, Wu_ln, Wstack, bmp);
    compute_deg<<<(NE + 255) / 256, 256, 0, stream>>>(nl_edge, ln_edge, idl, idn);
    scan1<<<2 * SNB, 256, 0, stream>>>(idl, idn, bsum);
    scan2<<<1, 128, 0, stream>>>(bsum, bbase);
    scan3<<<2 * SNB, 256, 0, stream>>>(idl, idn, bbase, offL, offN, curL, curN, deg_l, deg_n);
    fill_csr<<<(NE + 255) / 256, 256, 0, stream>>>(nl_edge, ln_edge, curL, curN, adjL, adjN);
    pool_counts<<<1, 64, 0, stream>>>(batch_link, cnt);

    // ---- layer 1 ----
    gather_sum8_2<<<dim3((NL * FR + 255) / 256, 2), 256, 0, stream>>>(
        offL, adjL, x_node, Sl, offN, adjN, x_link, Sn);
    gemm_update_l1_2<<<dim3((NL + BM - 1) / BM, 2), 256, 0, stream>>>(
        Sl, x_link, deg_l, Sn, x_node, deg_n, Wstack, bmp, bu_nl, bu_ln, xl, xn, NL);

    // ---- layer 2 ----
    gather_sum2<<<dim3((NL + 7) / 8, 2), 256, 0, stream>>>(
        offL, adjL, xn, Sl, offN, adjN, xl, Sn);
    gemm_update3<<<dim3((NL + BM - 1) / BM, 2), 256, 0, stream>>>(
        Sl, xl, deg_l, Sn, xn, deg_n, Wstack, bmp, bu_nl, bu_ln, xl, xn, NL);

    pool_sum<<<(NL + PR - 1) / PR, 256, 0, stream>>>(xl, batch_link, sums);
    pool_final<<<(NG * H) / 256, 256, 0, stream>>>(sums, cnt, (float*)d_out);
}